// Round 15
// baseline (174.342 us; speedup 1.0000x reference)
//
#include <hip/hip_runtime.h>
#include <math.h>

// Problem dims (fixed by reference)
#define BDIM 4
#define TDIM 4096
#define DDIM 1024
#define MDIM (BDIM * TDIM)   // 16384

// scan chunking
#define NC  64
#define LCH 64
static_assert(NC * LCH == TDIM, "chunking");

typedef __attribute__((ext_vector_type(8))) short short8;
typedef __attribute__((ext_vector_type(4))) float f32x4;

__device__ __forceinline__ unsigned short f2bf(float f) {
  unsigned int u = __float_as_uint(f);
  unsigned int r = (u + 0x7fffu + ((u >> 16) & 1u)) >> 16;  // RNE
  return (unsigned short)r;
}
__device__ __forceinline__ float bf2f(unsigned short h) {
  return __uint_as_float(((unsigned int)h) << 16);
}
__device__ __forceinline__ float sigmoidf_(float x) {
  return 1.0f / (1.0f + expf(-x));
}

// ---------------- prep: x -> bf16 ----------------
__global__ __launch_bounds__(256) void prep_x_kernel(const float* __restrict__ x,
                                                     unsigned short* __restrict__ xh,
                                                     int n4) {
  int i = blockIdx.x * 256 + threadIdx.x;
  if (i >= n4) return;
  float4 f = ((const float4*)x)[i];
  ushort4 h;
  h.x = f2bf(f.x);
  h.y = f2bf(f.y);
  h.z = f2bf(f.z);
  h.w = f2bf(f.w);
  ((ushort4*)xh)[i] = h;
}

// ---------------- prep: W [K][N] f32 -> transposed [N][K] bf16 ----------------
__global__ __launch_bounds__(256) void wprep_kernel(const float* __restrict__ in,
                                                    unsigned short* __restrict__ oh,
                                                    int K, int N) {
  __shared__ float t[64][65];
  int n0 = blockIdx.x * 64;
  int k0 = blockIdx.y * 64;
#pragma unroll
  for (int i = 0; i < 16; ++i) {
    int idx = i * 256 + threadIdx.x;
    int r = idx >> 6, c = idx & 63;
    t[r][c] = in[(size_t)(k0 + r) * N + (n0 + c)];
  }
  __syncthreads();
#pragma unroll
  for (int i = 0; i < 16; ++i) {
    int idx = i * 256 + threadIdx.x;
    int rn = idx >> 6, ck = idx & 63;
    oh[(size_t)(n0 + rn) * K + (k0 + ck)] = f2bf(t[ck][rn]);
  }
}

// ---------------- 128x128 2-wave GEMM, 4 blocks/CU -----------------------------
// Each wave owns a 64x128 output tile (acc[4][8]) -> 43.7 FLOP per LDS byte
// (vs 32.8 at 64x64), cutting LDS-read traffic 25% at equal MFMA work.
// A+B single-buffered LDS: A tile @0 (16384 B = 128 rows x 128 B), B @16384.
// Swizzle: physical = row*128 + (colByte ^ ((row&7)<<4)); +64 kk-half offset
// applied INSIDE the XOR. global_load_lds writes linearly; source carries the
// inverse swizzle. Loop: {stage -> vmcnt(0) -> barrier -> reads+MFMA -> barrier}.
// Overlap via 4 co-resident blocks/CU (m97/m114 mechanism, verified round 12/14).
// EPI=1: ssm phase-1 fused into the epilogue; each wave owns one whole chunk
// (chunk = mtile*2 + wave): h = sum_r delta^(63-r) v_r via per-thread weighted
// sum + 2 quad-shuffles -> chunkp (separate producer buffer, round-14 lesson).

#define BARRIER()                                  \
  do {                                             \
    asm volatile("" ::: "memory");                 \
    __builtin_amdgcn_s_barrier();                  \
    asm volatile("" ::: "memory");                 \
  } while (0)

#define RD_A(SET, BK)                                                           \
  _Pragma("unroll") for (int m = 0; m < 4; ++m)                                 \
      SET[m] = *(const short8*)(ldsb + (((BK) ? baseA1 : baseA0) + m * 2048));

#define RD_B(SET, BK)                                                           \
  _Pragma("unroll") for (int n = 0; n < 8; ++n)                                 \
      SET[n] = *(const short8*)(ldsb + 16384 + (((BK) ? baseB1 : baseB0) +      \
                                                n * 2048));

#define MFMA32(ASET, BSET)                                                      \
  _Pragma("unroll") for (int m = 0; m < 4; ++m)                                 \
      _Pragma("unroll") for (int n = 0; n < 8; ++n)                             \
          acc[m][n] = __builtin_amdgcn_mfma_f32_16x16x32_bf16(                  \
              ASET[m], BSET[n], acc[m][n], 0, 0, 0);

// one staging load: 16B/lane; dst = wave-uniform LDS base (+lane*16 by HW).
// Unit S = 2048 B (128 threads x 16 B); 8 units per 16 KB tile.
#define STAGE(PTR, S, BUFB, KOFF)                                               \
  __builtin_amdgcn_global_load_lds(                                             \
      (const __attribute__((address_space(1))) unsigned int*)((PTR) + off##S +  \
                                                              (KOFF)),          \
      (__attribute__((address_space(3))) unsigned int*)((char*)lds + (BUFB) +   \
                                                        (S) * 2048 +            \
                                                        wave * 1024),           \
      16, 0, 0);

#define STAGE_ALL(PTR, BUFB, KOFF)                                              \
  STAGE(PTR, 0, BUFB, KOFF) STAGE(PTR, 1, BUFB, KOFF)                           \
  STAGE(PTR, 2, BUFB, KOFF) STAGE(PTR, 3, BUFB, KOFF)                           \
  STAGE(PTR, 4, BUFB, KOFF) STAGE(PTR, 5, BUFB, KOFF)                           \
  STAGE(PTR, 6, BUFB, KOFF) STAGE(PTR, 7, BUFB, KOFF)

// EPI 0: f32 out + bias (N = nNt*128). EPI 1: fused v|g bf16 + chunkp partials.
template <int EPI>
__global__ __launch_bounds__(128, 2) void gemm128w(const unsigned short* __restrict__ A,
                                                   const unsigned short* __restrict__ B,
                                                   const float* __restrict__ bias,
                                                   float* __restrict__ outF,
                                                   unsigned short* __restrict__ outV,
                                                   unsigned short* __restrict__ outG,
                                                   const float* __restrict__ Adec,
                                                   float* __restrict__ chunkp,
                                                   int nNt, int K) {
  __shared__ unsigned short lds[16384];  // 32 KiB total: A 16 KB + B 16 KB

  // T1: XCD-aware swizzle (gridDim.x % 8 == 0 for all our launches)
  int cpx = gridDim.x >> 3;
  int bid = blockIdx.x;
  int swz = (bid & 7) * cpx + (bid >> 3);
  int mtile = swz / nNt, ntile = swz % nNt;

  int tid = threadIdx.x;
  int wave = tid >> 6, lane = tid & 63;  // 2 waves, each 64 rows x 128 cols
  int rA = wave * 64 + (lane & 15);
  int rB = lane & 15;
  int kq2 = (lane >> 4) * 16;  // k-quad offset in BYTES

  // hoisted swizzled read bases; +64 applied INSIDE the XOR
  int baseA0 = ((rA << 7) + kq2) ^ ((rA & 7) << 4);
  int baseA1 = ((rA << 7) + kq2 + 64) ^ ((rA & 7) << 4);
  int baseB0 = ((rB << 7) + kq2) ^ ((rB & 7) << 4);
  int baseB1 = ((rB << 7) + kq2 + 64) ^ ((rB & 7) << 4);
  const char* ldsb = (const char*)lds;

  // hoisted staging source offsets (inverse swizzle; tile = 128 rows x 128 B)
#define MKOFF(S) \
  ({ int Lt = (S) * 2048 + tid * 16; int P = Lt ^ (((Lt >> 7) & 7) << 4); \
     ((P >> 7) * (K << 1)) + (P & 127); })
  int off0 = MKOFF(0), off1 = MKOFF(1), off2 = MKOFF(2), off3 = MKOFF(3);
  int off4 = MKOFF(4), off5 = MKOFF(5), off6 = MKOFF(6), off7 = MKOFF(7);
#undef MKOFF

  const char* AgB = (const char*)(A + (size_t)(mtile * 128) * K);
  const char* BgB = (const char*)(B + (size_t)(ntile * 128) * K);

  f32x4 acc[4][8] = {};
  short8 af[4], bf[8];

  int NT = K >> 6;  // 16
  for (int t = 0; t < NT; ++t) {
    int k0 = t << 7;  // byte advance: 64 elems * 2B per K-tile
    STAGE_ALL(AgB, 0, k0)
    STAGE_ALL(BgB, 16384, k0)
    asm volatile("s_waitcnt vmcnt(0)" ::: "memory");
    BARRIER();
    RD_A(af, 0);
    RD_B(bf, 0);
    MFMA32(af, bf);
    RD_A(af, 1);
    RD_B(bf, 1);
    MFMA32(af, bf);
    BARRIER();  // WAR: all reads done before next tile's stage overwrites
  }

  // epilogue: C/D layout col = lane&15, row = (lane>>4)*4 + j
  int q = lane >> 4;
  int row0 = mtile * 128 + wave * 64 + (q << 2);
  int col0 = ntile * 128 + (lane & 15);

  if (EPI == 0) {
#pragma unroll
    for (int m = 0; m < 4; ++m) {
#pragma unroll
      for (int n = 0; n < 8; ++n) {
        int col = col0 + n * 16;
        float bv = bias[col];
#pragma unroll
        for (int j = 0; j < 4; ++j) {
          int row = row0 + m * 16 + j;
          outF[(size_t)row * (nNt * 128) + col] = acc[m][n][j] + bv;
        }
      }
    }
  } else if (col0 >= DDIM) {
    // g half: sigmoid -> bf16
#pragma unroll
    for (int m = 0; m < 4; ++m) {
#pragma unroll
      for (int n = 0; n < 8; ++n) {
        int col = col0 + n * 16;
        float bv = bias[col];
#pragma unroll
        for (int j = 0; j < 4; ++j) {
          int row = row0 + m * 16 + j;
          outG[(size_t)row * DDIM + (col - DDIM)] = f2bf(sigmoidf_(acc[m][n][j] + bv));
        }
      }
    }
  } else {
    // v half: write bf16 v AND fused ssm-phase1 per-chunk weighted sum.
    // chunk-local row of acc[m][*][j] is r = q*4 + m*16 + j (covers 0..63
    // across the 4 lane-quads); weight = delta^(63-r).
    float partial[8];
#pragma unroll
    for (int n = 0; n < 8; ++n) {
      int col = col0 + n * 16;
      float bv = bias[col];
      float dec = sigmoidf_(Adec[col]);
      float l2d = __log2f(dec);
      float p = 0.f;
#pragma unroll
      for (int m = 0; m < 4; ++m) {
#pragma unroll
        for (int j = 0; j < 4; ++j) {
          int row = row0 + m * 16 + j;
          unsigned short ush = f2bf(acc[m][n][j] + bv);
          outV[(size_t)row * DDIM + col] = ush;
          float w = exp2f((float)(63 - (q * 4 + m * 16 + j)) * l2d);
          p = fmaf(w, bf2f(ush), p);
        }
      }
      partial[n] = p;
    }
    // reduce over the 4 lane-quads (lanes l, l^16, l^32, l^48)
#pragma unroll
    for (int n = 0; n < 8; ++n) {
      partial[n] += __shfl_xor(partial[n], 16, 64);
      partial[n] += __shfl_xor(partial[n], 32, 64);
    }
    if (q == 0) {
      int chunkg = mtile * 2 + wave;  // global chunk id = b*NC + c
#pragma unroll
      for (int n = 0; n < 8; ++n)
        chunkp[(size_t)chunkg * DDIM + col0 + n * 16] = partial[n];
    }
  }
}

// ---------------- SSM chunked scan (v, g in bf16) ----------------
// phase 2: exclusive carry scan across chunks. Reads chunkp, writes chunkh.
__global__ __launch_bounds__(256) void ssm_phase2(const float* __restrict__ A,
                                                  const float* __restrict__ chunkp,
                                                  float* __restrict__ chunkh) {
  int idx = blockIdx.x * 256 + threadIdx.x;  // 0..B*D-1
  int b = idx >> 10, d = idx & 1023;
  float dec = sigmoidf_(A[d]);
  float dL = dec;
#pragma unroll
  for (int i = 0; i < 6; ++i) dL *= dL;  // dec^64
  float hv[NC];
#pragma unroll
  for (int c = 0; c < NC; ++c) hv[c] = chunkp[(size_t)(b * NC + c) * DDIM + d];
  float carry = 0.f;
#pragma unroll
  for (int c = 0; c < NC; ++c) {
    float local = hv[c];
    chunkh[(size_t)(b * NC + c) * DDIM + d] = carry;
    carry = fmaf(dL, carry, local);
  }
}

__global__ __launch_bounds__(256) void ssm_phase3(const unsigned short* __restrict__ v,
                                                  const unsigned short* __restrict__ g,
                                                  const float* __restrict__ A,
                                                  const float* __restrict__ C,
                                                  const float* __restrict__ chunkh,
                                                  unsigned short* __restrict__ ybf) {
  int b = blockIdx.y, c = blockIdx.x;
  int d0 = threadIdx.x * 4;
  float4 a4 = *(const float4*)&A[d0];
  float4 c4 = *(const float4*)&C[d0];
  float dx = sigmoidf_(a4.x), dy = sigmoidf_(a4.y), dz = sigmoidf_(a4.z), dw = sigmoidf_(a4.w);
  float4 h0 = *(const float4*)&chunkh[(size_t)(b * NC + c) * DDIM + d0];
  float hx = h0.x, hy = h0.y, hz = h0.z, hw = h0.w;
  size_t base = ((size_t)b * TDIM + (size_t)c * LCH) * DDIM + d0;
  const ushort4* vp = (const ushort4*)(v + base);
  const ushort4* gp = (const ushort4*)(g + base);
  ushort4* yp = (ushort4*)(ybf + base);
#pragma unroll 4
  for (int i = 0; i < LCH; ++i) {
    ushort4 vv = vp[(size_t)i * (DDIM / 4)];
    ushort4 gg = gp[(size_t)i * (DDIM / 4)];
    hx = fmaf(dx, hx, bf2f(vv.x));
    hy = fmaf(dy, hy, bf2f(vv.y));
    hz = fmaf(dz, hz, bf2f(vv.z));
    hw = fmaf(dw, hw, bf2f(vv.w));
    ushort4 yy;
    yy.x = f2bf(bf2f(gg.x) * c4.x * hx);
    yy.y = f2bf(bf2f(gg.y) * c4.y * hy);
    yy.z = f2bf(bf2f(gg.z) * c4.z * hz);
    yy.w = f2bf(bf2f(gg.w) * c4.w * hw);
    yp[(size_t)i * (DDIM / 4)] = yy;
  }
}

extern "C" void kernel_launch(void* const* d_in, const int* in_sizes, int n_in,
                              void* d_out, int out_size, void* d_ws, size_t ws_size,
                              hipStream_t stream) {
  const float* x = (const float*)d_in[0];
  const float* W_in = (const float*)d_in[1];
  const float* b_in = (const float*)d_in[2];
  const float* A = (const float*)d_in[3];
  const float* C = (const float*)d_in[4];
  const float* W_out = (const float*)d_in[5];
  const float* b_out = (const float*)d_in[6];
  float* out = (float*)d_out;

  // workspace carve (~143 MB)
  char* ws = (char*)d_ws;
  const size_t MK = (size_t)MDIM * DDIM;  // 16,777,216
  unsigned short* xh = (unsigned short*)ws;    ws += MK * 2;                       // 33.5 MB
  unsigned short* winh = (unsigned short*)ws;  ws += (size_t)2 * DDIM * DDIM * 2;  // 4.2 MB
  unsigned short* wouth = (unsigned short*)ws; ws += (size_t)DDIM * DDIM * 2;      // 2.1 MB
  unsigned short* v = (unsigned short*)ws;     ws += MK * 2;                       // 33.5 MB
  unsigned short* g = (unsigned short*)ws;     ws += MK * 2;                       // 33.5 MB
  unsigned short* ybf = (unsigned short*)ws;   ws += MK * 2;                       // 33.5 MB
  float* chunkp = (float*)ws;                  ws += (size_t)BDIM * NC * DDIM * 4; // 1.0 MB
  float* chunkh = (float*)ws;                  ws += (size_t)BDIM * NC * DDIM * 4; // 1.0 MB

  // prep
  prep_x_kernel<<<(int)(MK / 4 / 256), 256, 0, stream>>>(x, xh, (int)(MK / 4));
  wprep_kernel<<<dim3(2 * DDIM / 64, DDIM / 64), 256, 0, stream>>>(W_in, winh, DDIM, 2 * DDIM);
  wprep_kernel<<<dim3(DDIM / 64, DDIM / 64), 256, 0, stream>>>(W_out, wouth, DDIM, DDIM);

  // fused GEMM1: [v | g] = x @ W_in + b_in ; v bf16 (+ fused phase1 -> chunkp),
  // g = sigmoid -> bf16
  gemm128w<1><<<(MDIM / 128) * 16, 128, 0, stream>>>(xh, winh, b_in, nullptr, v, g,
                                                     A, chunkp, 16, DDIM);

  // chunked scan (phase1 fused into GEMM1 epilogue; chunkp -> chunkh)
  ssm_phase2<<<(BDIM * DDIM) / 256, 256, 0, stream>>>(A, chunkp, chunkh);
  ssm_phase3<<<dim3(NC, BDIM), 256, 0, stream>>>(v, g, A, C, chunkh, ybf);

  // GEMM2: out = y @ W_out + b_out
  gemm128w<0><<<(MDIM / 128) * 8, 128, 0, stream>>>(ybf, wouth, b_out, out, nullptr, nullptr,
                                                    nullptr, nullptr, 8, DDIM);
}

// Round 16
// 168.309 us; speedup vs baseline: 1.0358x; 1.0358x over previous
//
#include <hip/hip_runtime.h>
#include <math.h>

// Problem dims (fixed by reference)
#define BDIM 4
#define TDIM 4096
#define DDIM 1024
#define MDIM (BDIM * TDIM)   // 16384

// scan chunking
#define NC  64
#define LCH 64
static_assert(NC * LCH == TDIM, "chunking");

typedef __attribute__((ext_vector_type(8))) short short8;
typedef __attribute__((ext_vector_type(4))) float f32x4;

__device__ __forceinline__ unsigned short f2bf(float f) {
  unsigned int u = __float_as_uint(f);
  unsigned int r = (u + 0x7fffu + ((u >> 16) & 1u)) >> 16;  // RNE
  return (unsigned short)r;
}
__device__ __forceinline__ float bf2f(unsigned short h) {
  return __uint_as_float(((unsigned int)h) << 16);
}
__device__ __forceinline__ float sigmoidf_(float x) {
  return 1.0f / (1.0f + expf(-x));
}

// ---------------- prep: x -> bf16 ----------------
__global__ __launch_bounds__(256) void prep_x_kernel(const float* __restrict__ x,
                                                     unsigned short* __restrict__ xh,
                                                     int n4) {
  int i = blockIdx.x * 256 + threadIdx.x;
  if (i >= n4) return;
  float4 f = ((const float4*)x)[i];
  ushort4 h;
  h.x = f2bf(f.x);
  h.y = f2bf(f.y);
  h.z = f2bf(f.z);
  h.w = f2bf(f.w);
  ((ushort4*)xh)[i] = h;
}

// ---------------- prep: W [K][N] f32 -> transposed [N][K] bf16 ----------------
__global__ __launch_bounds__(256) void wprep_kernel(const float* __restrict__ in,
                                                    unsigned short* __restrict__ oh,
                                                    int K, int N) {
  __shared__ float t[64][65];
  int n0 = blockIdx.x * 64;
  int k0 = blockIdx.y * 64;
#pragma unroll
  for (int i = 0; i < 16; ++i) {
    int idx = i * 256 + threadIdx.x;
    int r = idx >> 6, c = idx & 63;
    t[r][c] = in[(size_t)(k0 + r) * N + (n0 + c)];
  }
  __syncthreads();
#pragma unroll
  for (int i = 0; i < 16; ++i) {
    int idx = i * 256 + threadIdx.x;
    int rn = idx >> 6, ck = idx & 63;
    oh[(size_t)(n0 + rn) * K + (k0 + ck)] = f2bf(t[ck][rn]);
  }
}

// ---------------- 128x128 4-wave GEMM, 4 blocks/CU (m97/m114 mechanism) -------
// A+B single-buffered LDS: A tile @0 (16384 B = 128 rows x 128 B), B @16384.
// Swizzle: physical = row*128 + (colByte ^ ((row&7)<<4)); +64 kk-half offset
// applied INSIDE the XOR. global_load_lds writes linearly; source carries the
// inverse swizzle. Loop: {stage -> vmcnt(0) -> barrier -> reads+MFMA -> barrier}.
// Overlap via 4 co-resident blocks/CU (verified rounds 12/14: 803-828 TF).
// Per-wave tile is 64x64 (64 AGPR + 60 VGPR = 124 regs) — the occupancy/reuse
// frontier: bigger per-wave tiles (128 AGPR) cap at 2 waves/SIMD and regress
// (round 15: 16% occupancy, -20%).
// EPI=1: ssm phase-1 fused into the epilogue — each (chunk, col) is owned by
// exactly one block: h = sum_r delta^(63-r) v_r = per-thread weighted sum +
// 2 quad-shuffles -> chunkp (separate producer buffer; in-place RMW raced
// across graph replays in round 13).

#define BARRIER()                                  \
  do {                                             \
    asm volatile("" ::: "memory");                 \
    __builtin_amdgcn_s_barrier();                  \
    asm volatile("" ::: "memory");                 \
  } while (0)

#define RD_A(SET, BK)                                                           \
  _Pragma("unroll") for (int m = 0; m < 4; ++m)                                 \
      SET[m] = *(const short8*)(ldsb + (((BK) ? baseA1 : baseA0) + m * 2048));

#define RD_B(SET, BK)                                                           \
  _Pragma("unroll") for (int n = 0; n < 4; ++n)                                 \
      SET[n] = *(const short8*)(ldsb + 16384 + (((BK) ? baseB1 : baseB0) +      \
                                                n * 2048));

#define MFMA16(ASET, BSET)                                                      \
  _Pragma("unroll") for (int m = 0; m < 4; ++m)                                 \
      _Pragma("unroll") for (int n = 0; n < 4; ++n)                             \
          acc[m][n] = __builtin_amdgcn_mfma_f32_16x16x32_bf16(                  \
              ASET[m], BSET[n], acc[m][n], 0, 0, 0);

// one staging load: 16B/lane; dst = wave-uniform LDS base (+lane*16 by HW).
#define STAGE(PTR, S, BUFB, KOFF)                                               \
  __builtin_amdgcn_global_load_lds(                                             \
      (const __attribute__((address_space(1))) unsigned int*)((PTR) + off##S +  \
                                                              (KOFF)),          \
      (__attribute__((address_space(3))) unsigned int*)((char*)lds + (BUFB) +   \
                                                        (S) * 4096 +            \
                                                        wave * 1024),           \
      16, 0, 0);

// EPI 0: f32 out + bias (N = nNt*128). EPI 1: fused v|g bf16 + chunkp partials.
template <int EPI>
__global__ __launch_bounds__(256, 4) void gemm128(const unsigned short* __restrict__ A,
                                                  const unsigned short* __restrict__ B,
                                                  const float* __restrict__ bias,
                                                  float* __restrict__ outF,
                                                  unsigned short* __restrict__ outV,
                                                  unsigned short* __restrict__ outG,
                                                  const float* __restrict__ Adec,
                                                  float* __restrict__ chunkp,
                                                  int nNt, int K) {
  __shared__ unsigned short lds[16384];  // 32 KiB total: A 16 KB + B 16 KB

  // T1: XCD-aware swizzle (gridDim.x % 8 == 0 for all our launches)
  int cpx = gridDim.x >> 3;
  int bid = blockIdx.x;
  int swz = (bid & 7) * cpx + (bid >> 3);
  int mtile = swz / nNt, ntile = swz % nNt;

  int tid = threadIdx.x;
  int wave = tid >> 6, lane = tid & 63;
  int wm = wave >> 1, wn = wave & 1;  // 2 x 2 waves, each 64x64 output
  int rA = wm * 64 + (lane & 15);
  int rB = wn * 64 + (lane & 15);
  int kq2 = (lane >> 4) * 16;  // k-quad offset in BYTES

  // hoisted swizzled read bases; +64 applied INSIDE the XOR
  int baseA0 = ((rA << 7) + kq2) ^ ((rA & 7) << 4);
  int baseA1 = ((rA << 7) + kq2 + 64) ^ ((rA & 7) << 4);
  int baseB0 = ((rB << 7) + kq2) ^ ((rB & 7) << 4);
  int baseB1 = ((rB << 7) + kq2 + 64) ^ ((rB & 7) << 4);
  const char* ldsb = (const char*)lds;

  // hoisted staging source offsets (inverse swizzle; tile = 128 rows x 128 B)
#define MKOFF(S) \
  ({ int Lt = (S) * 4096 + tid * 16; int P = Lt ^ (((Lt >> 7) & 7) << 4); \
     ((P >> 7) * (K << 1)) + (P & 127); })
  int off0 = MKOFF(0), off1 = MKOFF(1), off2 = MKOFF(2), off3 = MKOFF(3);
#undef MKOFF

  const char* AgB = (const char*)(A + (size_t)(mtile * 128) * K);
  const char* BgB = (const char*)(B + (size_t)(ntile * 128) * K);

  f32x4 acc[4][4] = {};
  short8 af[4], bf[4];

  int NT = K >> 6;  // 16
  for (int t = 0; t < NT; ++t) {
    int k0 = t << 7;  // byte advance: 64 elems * 2B per K-tile
    STAGE(AgB, 0, 0, k0) STAGE(AgB, 1, 0, k0)
    STAGE(AgB, 2, 0, k0) STAGE(AgB, 3, 0, k0)
    STAGE(BgB, 0, 16384, k0) STAGE(BgB, 1, 16384, k0)
    STAGE(BgB, 2, 16384, k0) STAGE(BgB, 3, 16384, k0)
    asm volatile("s_waitcnt vmcnt(0)" ::: "memory");
    BARRIER();
    RD_A(af, 0);
    RD_B(bf, 0);
    MFMA16(af, bf);
    RD_A(af, 1);
    RD_B(bf, 1);
    MFMA16(af, bf);
    BARRIER();  // WAR: all reads done before next tile's stage overwrites
  }

  // epilogue: C/D layout col = lane&15, row = (lane>>4)*4 + j
  int q = lane >> 4;
  int row0 = mtile * 128 + wm * 64 + (q << 2);
  int col0 = ntile * 128 + wn * 64 + (lane & 15);

  if (EPI == 0) {
#pragma unroll
    for (int m = 0; m < 4; ++m) {
#pragma unroll
      for (int n = 0; n < 4; ++n) {
        int col = col0 + n * 16;
        float bv = bias[col];
#pragma unroll
        for (int j = 0; j < 4; ++j) {
          int row = row0 + m * 16 + j;
          outF[(size_t)row * (nNt * 128) + col] = acc[m][n][j] + bv;
        }
      }
    }
  } else if (col0 >= DDIM) {
    // g half: sigmoid -> bf16
#pragma unroll
    for (int m = 0; m < 4; ++m) {
#pragma unroll
      for (int n = 0; n < 4; ++n) {
        int col = col0 + n * 16;
        float bv = bias[col];
#pragma unroll
        for (int j = 0; j < 4; ++j) {
          int row = row0 + m * 16 + j;
          outG[(size_t)row * DDIM + (col - DDIM)] = f2bf(sigmoidf_(acc[m][n][j] + bv));
        }
      }
    }
  } else {
    // v half: write bf16 v AND fused ssm-phase1 per-chunk weighted sum.
    // chunk-local row of acc[m][*][j] is r = q*4 + m*16 + j (covers 0..63
    // across the 4 lane-quads); weight = delta^(63-r).
    float partial[4];
#pragma unroll
    for (int n = 0; n < 4; ++n) {
      int col = col0 + n * 16;
      float bv = bias[col];
      float dec = sigmoidf_(Adec[col]);
      float l2d = __log2f(dec);
      float p = 0.f;
#pragma unroll
      for (int m = 0; m < 4; ++m) {
#pragma unroll
        for (int j = 0; j < 4; ++j) {
          int row = row0 + m * 16 + j;
          unsigned short ush = f2bf(acc[m][n][j] + bv);
          outV[(size_t)row * DDIM + col] = ush;
          float w = exp2f((float)(63 - (q * 4 + m * 16 + j)) * l2d);
          p = fmaf(w, bf2f(ush), p);
        }
      }
      partial[n] = p;
    }
    // reduce over the 4 lane-quads (lanes l, l^16, l^32, l^48)
#pragma unroll
    for (int n = 0; n < 4; ++n) {
      partial[n] += __shfl_xor(partial[n], 16, 64);
      partial[n] += __shfl_xor(partial[n], 32, 64);
    }
    if (q == 0) {
      int chunkg = mtile * 2 + wm;  // global chunk id = b*NC + c
#pragma unroll
      for (int n = 0; n < 4; ++n)
        chunkp[(size_t)chunkg * DDIM + col0 + n * 16] = partial[n];
    }
  }
}

// ---------------- SSM chunked scan (v, g in bf16) ----------------
// phase 2: exclusive carry scan across chunks. Reads chunkp, writes chunkh.
__global__ __launch_bounds__(256) void ssm_phase2(const float* __restrict__ A,
                                                  const float* __restrict__ chunkp,
                                                  float* __restrict__ chunkh) {
  int idx = blockIdx.x * 256 + threadIdx.x;  // 0..B*D-1
  int b = idx >> 10, d = idx & 1023;
  float dec = sigmoidf_(A[d]);
  float dL = dec;
#pragma unroll
  for (int i = 0; i < 6; ++i) dL *= dL;  // dec^64
  float hv[NC];
#pragma unroll
  for (int c = 0; c < NC; ++c) hv[c] = chunkp[(size_t)(b * NC + c) * DDIM + d];
  float carry = 0.f;
#pragma unroll
  for (int c = 0; c < NC; ++c) {
    float local = hv[c];
    chunkh[(size_t)(b * NC + c) * DDIM + d] = carry;
    carry = fmaf(dL, carry, local);
  }
}

__global__ __launch_bounds__(256) void ssm_phase3(const unsigned short* __restrict__ v,
                                                  const unsigned short* __restrict__ g,
                                                  const float* __restrict__ A,
                                                  const float* __restrict__ C,
                                                  const float* __restrict__ chunkh,
                                                  unsigned short* __restrict__ ybf) {
  int b = blockIdx.y, c = blockIdx.x;
  int d0 = threadIdx.x * 4;
  float4 a4 = *(const float4*)&A[d0];
  float4 c4 = *(const float4*)&C[d0];
  float dx = sigmoidf_(a4.x), dy = sigmoidf_(a4.y), dz = sigmoidf_(a4.z), dw = sigmoidf_(a4.w);
  float4 h0 = *(const float4*)&chunkh[(size_t)(b * NC + c) * DDIM + d0];
  float hx = h0.x, hy = h0.y, hz = h0.z, hw = h0.w;
  size_t base = ((size_t)b * TDIM + (size_t)c * LCH) * DDIM + d0;
  const ushort4* vp = (const ushort4*)(v + base);
  const ushort4* gp = (const ushort4*)(g + base);
  ushort4* yp = (ushort4*)(ybf + base);
#pragma unroll 4
  for (int i = 0; i < LCH; ++i) {
    ushort4 vv = vp[(size_t)i * (DDIM / 4)];
    ushort4 gg = gp[(size_t)i * (DDIM / 4)];
    hx = fmaf(dx, hx, bf2f(vv.x));
    hy = fmaf(dy, hy, bf2f(vv.y));
    hz = fmaf(dz, hz, bf2f(vv.z));
    hw = fmaf(dw, hw, bf2f(vv.w));
    ushort4 yy;
    yy.x = f2bf(bf2f(gg.x) * c4.x * hx);
    yy.y = f2bf(bf2f(gg.y) * c4.y * hy);
    yy.z = f2bf(bf2f(gg.z) * c4.z * hz);
    yy.w = f2bf(bf2f(gg.w) * c4.w * hw);
    yp[(size_t)i * (DDIM / 4)] = yy;
  }
}

extern "C" void kernel_launch(void* const* d_in, const int* in_sizes, int n_in,
                              void* d_out, int out_size, void* d_ws, size_t ws_size,
                              hipStream_t stream) {
  const float* x = (const float*)d_in[0];
  const float* W_in = (const float*)d_in[1];
  const float* b_in = (const float*)d_in[2];
  const float* A = (const float*)d_in[3];
  const float* C = (const float*)d_in[4];
  const float* W_out = (const float*)d_in[5];
  const float* b_out = (const float*)d_in[6];
  float* out = (float*)d_out;

  // workspace carve (~143 MB)
  char* ws = (char*)d_ws;
  const size_t MK = (size_t)MDIM * DDIM;  // 16,777,216
  unsigned short* xh = (unsigned short*)ws;    ws += MK * 2;                       // 33.5 MB
  unsigned short* winh = (unsigned short*)ws;  ws += (size_t)2 * DDIM * DDIM * 2;  // 4.2 MB
  unsigned short* wouth = (unsigned short*)ws; ws += (size_t)DDIM * DDIM * 2;      // 2.1 MB
  unsigned short* v = (unsigned short*)ws;     ws += MK * 2;                       // 33.5 MB
  unsigned short* g = (unsigned short*)ws;     ws += MK * 2;                       // 33.5 MB
  unsigned short* ybf = (unsigned short*)ws;   ws += MK * 2;                       // 33.5 MB
  float* chunkp = (float*)ws;                  ws += (size_t)BDIM * NC * DDIM * 4; // 1.0 MB
  float* chunkh = (float*)ws;                  ws += (size_t)BDIM * NC * DDIM * 4; // 1.0 MB

  // prep
  prep_x_kernel<<<(int)(MK / 4 / 256), 256, 0, stream>>>(x, xh, (int)(MK / 4));
  wprep_kernel<<<dim3(2 * DDIM / 64, DDIM / 64), 256, 0, stream>>>(W_in, winh, DDIM, 2 * DDIM);
  wprep_kernel<<<dim3(DDIM / 64, DDIM / 64), 256, 0, stream>>>(W_out, wouth, DDIM, DDIM);

  // fused GEMM1: [v | g] = x @ W_in + b_in ; v bf16 (+ fused phase1 -> chunkp),
  // g = sigmoid -> bf16
  gemm128<1><<<(MDIM / 128) * 16, 256, 0, stream>>>(xh, winh, b_in, nullptr, v, g,
                                                    A, chunkp, 16, DDIM);

  // chunked scan (phase1 fused into GEMM1 epilogue; chunkp -> chunkh)
  ssm_phase2<<<(BDIM * DDIM) / 256, 256, 0, stream>>>(A, chunkp, chunkh);
  ssm_phase3<<<dim3(NC, BDIM), 256, 0, stream>>>(v, g, A, C, chunkh, ybf);

  // GEMM2: out = y @ W_out + b_out
  gemm128<0><<<(MDIM / 128) * 8, 256, 0, stream>>>(ybf, wouth, b_out, out, nullptr, nullptr,
                                                   nullptr, nullptr, 8, DDIM);
}